// Round 2
// baseline (1418.954 us; speedup 1.0000x reference)
//
#include <hip/hip_runtime.h>
#include <stdint.h>

#define N_NODES 100000
#define N_EDGES 600000
// D_IN = D_H = 128, D_OUT = 2
// All float tensors are fp32 on device; edge_index delivered as int32.

// K0: deg starts at 1.0 (self-loop)
__global__ void k_init_deg(float* __restrict__ deg) {
    int i = blockIdx.x * 256 + threadIdx.x;
    if (i < N_NODES) deg[i] = 1.0f;
}

// K1: deg[col[e]] += 1
__global__ void k_deg(const int* __restrict__ ei, float* __restrict__ deg) {
    int e = blockIdx.x * 256 + threadIdx.x;
    if (e < N_EDGES) atomicAdd(&deg[ei[N_EDGES + e]], 1.0f);
}

// K2: deg -> rsqrt(deg) in place (deg >= 1 always, no zero case)
__global__ void k_rsqrt(float* __restrict__ deg) {
    int i = blockIdx.x * 256 + threadIdx.x;
    if (i < N_NODES) deg[i] = rsqrtf(deg[i]);
}

// K3: h1 = x @ W1   [N,128] = [N,128]@[128,128] fp32
// block = 256 threads, 16 rows/block; thread computes 8 cols of one row
__global__ __launch_bounds__(256) void k_gemm1(const float* __restrict__ x,
                                               const float* __restrict__ W1,
                                               float* __restrict__ h1) {
    __shared__ float sx[16][129];  // +1 pad: xr[k] broadcast across 16 lanes, pad kills row aliasing
    int tid = threadIdx.x;
    int rowBase = blockIdx.x * 16;
    {
        const float4* xs = (const float4*)(x + (size_t)rowBase * 128);
        float4 v0 = xs[tid];          // 256 threads * 2 float4 = 2048 floats = 16*128
        float4 v1 = xs[tid + 256];
        int b0 = tid * 4;
        float* d0 = &sx[b0 >> 7][b0 & 127];
        d0[0] = v0.x; d0[1] = v0.y; d0[2] = v0.z; d0[3] = v0.w;
        int b1i = (tid + 256) * 4;
        float* d1 = &sx[b1i >> 7][b1i & 127];
        d1[0] = v1.x; d1[1] = v1.y; d1[2] = v1.z; d1[3] = v1.w;
    }
    __syncthreads();
    int r = tid >> 4;
    int c0 = (tid & 15) * 8;
    float a0 = 0, a1 = 0, a2 = 0, a3 = 0, a4 = 0, a5 = 0, a6 = 0, a7 = 0;
    const float* xr = sx[r];
#pragma unroll 4
    for (int k = 0; k < 128; k++) {
        float xv = xr[k];
        float4 w0 = *(const float4*)(W1 + k * 128 + c0);
        float4 w1 = *(const float4*)(W1 + k * 128 + c0 + 4);
        a0 = fmaf(xv, w0.x, a0);
        a1 = fmaf(xv, w0.y, a1);
        a2 = fmaf(xv, w0.z, a2);
        a3 = fmaf(xv, w0.w, a3);
        a4 = fmaf(xv, w1.x, a4);
        a5 = fmaf(xv, w1.y, a5);
        a6 = fmaf(xv, w1.z, a6);
        a7 = fmaf(xv, w1.w, a7);
    }
    float4* out = (float4*)(h1 + (size_t)(rowBase + r) * 128 + c0);
    out[0] = make_float4(a0, a1, a2, a3);
    out[1] = make_float4(a4, a5, a6, a7);
}

// K4: agg1 = h1 * dinv^2  (self-loop contribution; also serves as the zero-init)
__global__ void k_self1(const float* __restrict__ h1, const float* __restrict__ dinv,
                        float* __restrict__ agg1) {
    int g = blockIdx.x * 256 + threadIdx.x;  // one float4 per thread, exact grid
    int node = g >> 5;                        // 32 float4 per 128-col row
    float d = dinv[node];
    float d2 = d * d;
    float4 v = ((const float4*)h1)[g];
    v.x *= d2; v.y *= d2; v.z *= d2; v.w *= d2;
    ((float4*)agg1)[g] = v;
}

// K5: edge scatter layer 1: agg1[col] += h1[row] * dinv[row]*dinv[col]
// thread = (edge, 4-col chunk): coalesced float4 gather, 4 f32 atomics
__global__ void k_scatter1(const int* __restrict__ ei, const float* __restrict__ dinv,
                           const float* __restrict__ h1, float* __restrict__ agg1) {
    int g = blockIdx.x * 256 + threadIdx.x;
    int e = g >> 5;
    int c4 = (g & 31) * 4;
    int r = ei[e];
    int c = ei[N_EDGES + e];
    float norm = dinv[r] * dinv[c];
    float4 v = *(const float4*)(h1 + (size_t)r * 128 + c4);
    float* dst = agg1 + (size_t)c * 128 + c4;
    atomicAdd(dst + 0, v.x * norm);
    atomicAdd(dst + 1, v.y * norm);
    atomicAdd(dst + 2, v.z * norm);
    atomicAdd(dst + 3, v.w * norm);
}

// K6: fused bias1 + ReLU + GEMM2 ([N,128]@[128,2]) + self-loop init of agg2
// one wave (64 lanes) per row; float2 per lane; butterfly reduce
__global__ __launch_bounds__(256) void k_layer2(const float* __restrict__ agg1,
                                                const float* __restrict__ b1,
                                                const float* __restrict__ W2,
                                                const float* __restrict__ dinv,
                                                float* __restrict__ h2,
                                                float* __restrict__ agg2) {
    int g = blockIdx.x * 256 + threadIdx.x;
    int row = g >> 6;
    int lane = g & 63;
    float2 a = *(const float2*)(agg1 + (size_t)row * 128 + lane * 2);
    float2 bb = *(const float2*)(b1 + lane * 2);
    float v0 = fmaxf(a.x + bb.x, 0.0f);
    float v1 = fmaxf(a.y + bb.y, 0.0f);
    float4 w = *(const float4*)(W2 + lane * 4);  // rows 2l, 2l+1 of W2[128,2]
    float p0 = v0 * w.x + v1 * w.z;
    float p1 = v0 * w.y + v1 * w.w;
    for (int off = 32; off; off >>= 1) {
        p0 += __shfl_xor(p0, off);
        p1 += __shfl_xor(p1, off);
    }
    if (lane == 0) {
        float d = dinv[row];
        float d2 = d * d;
        *(float2*)(h2 + (size_t)row * 2) = make_float2(p0, p1);
        *(float2*)(agg2 + (size_t)row * 2) = make_float2(p0 * d2, p1 * d2);
    }
}

// K7: edge scatter layer 2 (2 cols)
__global__ void k_scatter2(const int* __restrict__ ei, const float* __restrict__ dinv,
                           const float* __restrict__ h2, float* __restrict__ agg2) {
    int e = blockIdx.x * 256 + threadIdx.x;
    if (e >= N_EDGES) return;
    int r = ei[e];
    int c = ei[N_EDGES + e];
    float norm = dinv[r] * dinv[c];
    float2 v = *(const float2*)(h2 + (size_t)r * 2);
    atomicAdd(agg2 + (size_t)c * 2 + 0, v.x * norm);
    atomicAdd(agg2 + (size_t)c * 2 + 1, v.y * norm);
}

// K8: out = agg2 + b2  (fp32 out)
__global__ void k_out(const float* __restrict__ agg2, const float* __restrict__ b2,
                      float* __restrict__ out) {
    int i = blockIdx.x * 256 + threadIdx.x;
    if (i >= N_NODES) return;
    float b0 = b2[0], b1v = b2[1];
    float2 a = *(const float2*)(agg2 + 2 * i);
    *(float2*)(out + 2 * i) = make_float2(a.x + b0, a.y + b1v);
}

extern "C" void kernel_launch(void* const* d_in, const int* in_sizes, int n_in,
                              void* d_out, int out_size, void* d_ws, size_t ws_size,
                              hipStream_t stream) {
    const float* x  = (const float*)d_in[0];   // [N,128] f32
    const int* ei   = (const int*)d_in[1];     // [2,E] int32
    const float* W1 = (const float*)d_in[2];   // [128,128] f32
    const float* b1 = (const float*)d_in[3];   // [128] f32
    const float* W2 = (const float*)d_in[4];   // [128,2] f32
    const float* b2 = (const float*)d_in[5];   // [2] f32
    float* out = (float*)d_out;                // [N,2] f32

    float* ws   = (float*)d_ws;
    float* deg  = ws;                    // N floats (becomes dinv in place)
    float* h1   = ws + 131072;           // N*128
    float* agg1 = h1 + 12800000;         // N*128
    float* h2   = agg1 + 12800000;       // N*2
    float* agg2 = h2 + 262144;           // N*2   (total ~105 MB)

    k_init_deg<<<391, 256, 0, stream>>>(deg);
    k_deg<<<2344, 256, 0, stream>>>(ei, deg);
    k_rsqrt<<<391, 256, 0, stream>>>(deg);
    k_gemm1<<<6250, 256, 0, stream>>>(x, W1, h1);
    k_self1<<<12500, 256, 0, stream>>>(h1, deg, agg1);
    k_scatter1<<<75000, 256, 0, stream>>>(ei, deg, h1, agg1);
    k_layer2<<<25000, 256, 0, stream>>>(agg1, b1, W2, deg, h2, agg2);
    k_scatter2<<<2344, 256, 0, stream>>>(ei, deg, h2, agg2);
    k_out<<<391, 256, 0, stream>>>(agg2, b2, out);
}

// Round 3
// 424.012 us; speedup vs baseline: 3.3465x; 3.3465x over previous
//
#include <hip/hip_runtime.h>
#include <stdint.h>

#define N_NODES 100000
#define N_EDGES 600000
// D_IN = D_H = 128, D_OUT = 2. All float tensors fp32; edge_index int32.

// ---------- CSR build ----------

__global__ void k_zero(int* __restrict__ cnt) {
    int i = blockIdx.x * 256 + threadIdx.x;
    if (i < N_NODES) cnt[i] = 0;
}

__global__ void k_count(const int* __restrict__ ei, int* __restrict__ cnt) {
    int e = blockIdx.x * 256 + threadIdx.x;
    if (e < N_EDGES) atomicAdd(&cnt[ei[N_EDGES + e]], 1);
}

// block-level inclusive scan (Hillis-Steele in LDS) + per-block sums
__global__ __launch_bounds__(256) void k_scanA(const int* __restrict__ cnt,
                                               int* __restrict__ incl,
                                               int* __restrict__ bsum) {
    __shared__ int s[256];
    int i = blockIdx.x * 256 + threadIdx.x;
    int v = (i < N_NODES) ? cnt[i] : 0;
    s[threadIdx.x] = v;
    __syncthreads();
    for (int d = 1; d < 256; d <<= 1) {
        int t = (threadIdx.x >= d) ? s[threadIdx.x - d] : 0;
        __syncthreads();
        s[threadIdx.x] += t;
        __syncthreads();
    }
    if (i < N_NODES) incl[i] = s[threadIdx.x];
    if (threadIdx.x == 255) bsum[blockIdx.x] = s[255];
}

// scan the 391 block sums (single block of 512)
__global__ __launch_bounds__(512) void k_scanB(const int* __restrict__ bsum,
                                               int* __restrict__ bbase) {
    __shared__ int s[512];
    int v = (threadIdx.x < 391) ? bsum[threadIdx.x] : 0;
    s[threadIdx.x] = v;
    __syncthreads();
    for (int d = 1; d < 512; d <<= 1) {
        int t = (threadIdx.x >= d) ? s[threadIdx.x - d] : 0;
        __syncthreads();
        s[threadIdx.x] += t;
        __syncthreads();
    }
    if (threadIdx.x < 391) bbase[threadIdx.x] = s[threadIdx.x] - v;  // exclusive
}

// finalize: exclusive offsets, cursor copy, dinv = rsqrt(cnt+1)
__global__ void k_scanC(const int* __restrict__ cnt, const int* __restrict__ incl,
                        const int* __restrict__ bbase, int* __restrict__ off,
                        int* __restrict__ cursor, float* __restrict__ dinv) {
    int i = blockIdx.x * 256 + threadIdx.x;
    if (i >= N_NODES) return;
    int cv = cnt[i];
    int ex = incl[i] + bbase[i >> 8] - cv;
    off[i] = ex;
    cursor[i] = ex;
    dinv[i] = rsqrtf((float)cv + 1.0f);
}

// bucket-scatter edges: edata[pos] = {src, norm}
__global__ void k_bucket(const int* __restrict__ ei, const float* __restrict__ dinv,
                         int* __restrict__ cursor, int2* __restrict__ edata) {
    int e = blockIdx.x * 256 + threadIdx.x;
    if (e >= N_EDGES) return;
    int r = ei[e];
    int c = ei[N_EDGES + e];
    int pos = atomicAdd(&cursor[c], 1);
    float nrm = dinv[r] * dinv[c];
    edata[pos] = make_int2(r, __float_as_int(nrm));
}

// ---------- compute ----------

// h1 = x @ W1   [N,128]=[N,128]@[128,128] fp32; 16 rows/block, 8 cols/thread
__global__ __launch_bounds__(256) void k_gemm1(const float* __restrict__ x,
                                               const float* __restrict__ W1,
                                               float* __restrict__ h1) {
    __shared__ float sx[16][129];
    int tid = threadIdx.x;
    int rowBase = blockIdx.x * 16;
    {
        const float4* xs = (const float4*)(x + (size_t)rowBase * 128);
        float4 v0 = xs[tid];
        float4 v1 = xs[tid + 256];
        int b0 = tid * 4;
        float* d0 = &sx[b0 >> 7][b0 & 127];
        d0[0] = v0.x; d0[1] = v0.y; d0[2] = v0.z; d0[3] = v0.w;
        int b1i = (tid + 256) * 4;
        float* d1 = &sx[b1i >> 7][b1i & 127];
        d1[0] = v1.x; d1[1] = v1.y; d1[2] = v1.z; d1[3] = v1.w;
    }
    __syncthreads();
    int r = tid >> 4;
    int c0 = (tid & 15) * 8;
    float a0 = 0, a1 = 0, a2 = 0, a3 = 0, a4 = 0, a5 = 0, a6 = 0, a7 = 0;
    const float* xr = sx[r];
#pragma unroll 4
    for (int k = 0; k < 128; k++) {
        float xv = xr[k];
        float4 w0 = *(const float4*)(W1 + k * 128 + c0);
        float4 w1 = *(const float4*)(W1 + k * 128 + c0 + 4);
        a0 = fmaf(xv, w0.x, a0);
        a1 = fmaf(xv, w0.y, a1);
        a2 = fmaf(xv, w0.z, a2);
        a3 = fmaf(xv, w0.w, a3);
        a4 = fmaf(xv, w1.x, a4);
        a5 = fmaf(xv, w1.y, a5);
        a6 = fmaf(xv, w1.z, a6);
        a7 = fmaf(xv, w1.w, a7);
    }
    float4* out = (float4*)(h1 + (size_t)(rowBase + r) * 128 + c0);
    out[0] = make_float4(a0, a1, a2, a3);
    out[1] = make_float4(a4, a5, a6, a7);
}

// Layer-1 aggregation (gather over CSR) fused with bias1+ReLU+GEMM2 epilogue.
// One wave per node; lane l owns cols 2l, 2l+1. Writes only h2[N,2].
__global__ __launch_bounds__(256) void k_agg1(const float* __restrict__ h1,
                                              const int2* __restrict__ edata,
                                              const int* __restrict__ off,
                                              const int* __restrict__ cnt,
                                              const float* __restrict__ dinv,
                                              const float* __restrict__ b1,
                                              const float* __restrict__ W2,
                                              float* __restrict__ h2) {
    int g = blockIdx.x * 256 + threadIdx.x;
    int node = g >> 6;   // exact grid: 25000 blocks * 4 waves = 100000 nodes
    int lane = g & 63;
    float d = dinv[node];
    float d2 = d * d;
    float2 a = *(const float2*)(h1 + (size_t)node * 128 + lane * 2);
    a.x *= d2; a.y *= d2;
    int o = off[node];
    int c = cnt[node];   // wave-uniform loop count: no divergence
    for (int i = 0; i < c; i++) {
        int2 sn = edata[o + i];
        float nrm = __int_as_float(sn.y);
        float2 v = *(const float2*)(h1 + (size_t)sn.x * 128 + lane * 2);
        a.x = fmaf(v.x, nrm, a.x);
        a.y = fmaf(v.y, nrm, a.y);
    }
    // epilogue: bias + ReLU + [1x128]@[128x2] via butterfly reduce
    float2 bb = *(const float2*)(b1 + lane * 2);
    float v0 = fmaxf(a.x + bb.x, 0.0f);
    float v1 = fmaxf(a.y + bb.y, 0.0f);
    float4 w = *(const float4*)(W2 + lane * 4);  // W2 rows 2l, 2l+1
    float p0 = v0 * w.x + v1 * w.z;
    float p1 = v0 * w.y + v1 * w.w;
    for (int offl = 32; offl; offl >>= 1) {
        p0 += __shfl_xor(p0, offl);
        p1 += __shfl_xor(p1, offl);
    }
    if (lane == 0) *(float2*)(h2 + (size_t)node * 2) = make_float2(p0, p1);
}

// Layer-2 aggregation: thread per node over same CSR; h2 is L2-resident (800 KB).
__global__ void k_agg2(const float* __restrict__ h2, const int2* __restrict__ edata,
                       const int* __restrict__ off, const int* __restrict__ cnt,
                       const float* __restrict__ dinv, const float* __restrict__ b2,
                       float* __restrict__ out) {
    int n = blockIdx.x * 256 + threadIdx.x;
    if (n >= N_NODES) return;
    float d = dinv[n];
    float d2 = d * d;
    float2 h = *(const float2*)(h2 + (size_t)n * 2);
    float o0 = h.x * d2, o1 = h.y * d2;
    int o = off[n], c = cnt[n];
    for (int i = 0; i < c; i++) {
        int2 sn = edata[o + i];
        float nrm = __int_as_float(sn.y);
        float2 v = *(const float2*)(h2 + (size_t)sn.x * 2);
        o0 = fmaf(v.x, nrm, o0);
        o1 = fmaf(v.y, nrm, o1);
    }
    *(float2*)(out + (size_t)n * 2) = make_float2(o0 + b2[0], o1 + b2[1]);
}

extern "C" void kernel_launch(void* const* d_in, const int* in_sizes, int n_in,
                              void* d_out, int out_size, void* d_ws, size_t ws_size,
                              hipStream_t stream) {
    const float* x  = (const float*)d_in[0];   // [N,128]
    const int* ei   = (const int*)d_in[1];     // [2,E] int32
    const float* W1 = (const float*)d_in[2];   // [128,128]
    const float* b1 = (const float*)d_in[3];   // [128]
    const float* W2 = (const float*)d_in[4];   // [128,2]
    const float* b2 = (const float*)d_in[5];   // [2]
    float* out = (float*)d_out;                // [N,2]

    char* w = (char*)d_ws;
    int*   cnt    = (int*)w;                      w += 100096 * 4;
    int*   incl   = (int*)w;                      w += 100096 * 4;
    int*   bsum   = (int*)w;                      w += 512 * 4;
    int*   bbase  = (int*)w;                      w += 512 * 4;
    int*   off    = (int*)w;                      w += 100096 * 4;
    int*   cursor = (int*)w;                      w += 100096 * 4;
    float* dinv   = (float*)w;                    w += 100096 * 4;
    int2*  edata  = (int2*)w;                     w += (size_t)N_EDGES * 8;
    float* h1     = (float*)w;                    w += (size_t)N_NODES * 128 * 4;
    float* h2     = (float*)w;                    // N*2 floats

    k_zero  <<<391, 256, 0, stream>>>(cnt);
    k_count <<<2344, 256, 0, stream>>>(ei, cnt);
    k_scanA <<<391, 256, 0, stream>>>(cnt, incl, bsum);
    k_scanB <<<1, 512, 0, stream>>>(bsum, bbase);
    k_scanC <<<391, 256, 0, stream>>>(cnt, incl, bbase, off, cursor, dinv);
    k_bucket<<<2344, 256, 0, stream>>>(ei, dinv, cursor, edata);
    k_gemm1 <<<6250, 256, 0, stream>>>(x, W1, h1);
    k_agg1  <<<25000, 256, 0, stream>>>(h1, edata, off, cnt, dinv, b1, W2, h2);
    k_agg2  <<<391, 256, 0, stream>>>(h2, edata, off, cnt, dinv, b2, out);
}

// Round 4
// 293.249 us; speedup vs baseline: 4.8387x; 1.4459x over previous
//
#include <hip/hip_runtime.h>
#include <stdint.h>

#define N_NODES 100000
#define N_EDGES 600000
// D_IN = D_H = 128, D_OUT = 2. All float tensors fp32; edge_index int32.

// ---------- CSR build ----------

__global__ void k_zero(int* __restrict__ cnt) {
    int i = blockIdx.x * 256 + threadIdx.x;
    if (i < N_NODES) cnt[i] = 0;
}

__global__ void k_count(const int* __restrict__ ei, int* __restrict__ cnt) {
    int e = blockIdx.x * 256 + threadIdx.x;
    if (e < N_EDGES) atomicAdd(&cnt[ei[N_EDGES + e]], 1);
}

// block-level inclusive scan (Hillis-Steele in LDS) + per-block sums
__global__ __launch_bounds__(256) void k_scanA(const int* __restrict__ cnt,
                                               int* __restrict__ incl,
                                               int* __restrict__ bsum) {
    __shared__ int s[256];
    int i = blockIdx.x * 256 + threadIdx.x;
    int v = (i < N_NODES) ? cnt[i] : 0;
    s[threadIdx.x] = v;
    __syncthreads();
    for (int d = 1; d < 256; d <<= 1) {
        int t = (threadIdx.x >= d) ? s[threadIdx.x - d] : 0;
        __syncthreads();
        s[threadIdx.x] += t;
        __syncthreads();
    }
    if (i < N_NODES) incl[i] = s[threadIdx.x];
    if (threadIdx.x == 255) bsum[blockIdx.x] = s[255];
}

// scan the 391 block sums (single block of 512)
__global__ __launch_bounds__(512) void k_scanB(const int* __restrict__ bsum,
                                               int* __restrict__ bbase) {
    __shared__ int s[512];
    int v = (threadIdx.x < 391) ? bsum[threadIdx.x] : 0;
    s[threadIdx.x] = v;
    __syncthreads();
    for (int d = 1; d < 512; d <<= 1) {
        int t = (threadIdx.x >= d) ? s[threadIdx.x - d] : 0;
        __syncthreads();
        s[threadIdx.x] += t;
        __syncthreads();
    }
    if (threadIdx.x < 391) bbase[threadIdx.x] = s[threadIdx.x] - v;  // exclusive
}

// finalize: exclusive offsets, cursor copy, dinv = rsqrt(cnt+1)
__global__ void k_scanC(const int* __restrict__ cnt, const int* __restrict__ incl,
                        const int* __restrict__ bbase, int* __restrict__ off,
                        int* __restrict__ cursor, float* __restrict__ dinv) {
    int i = blockIdx.x * 256 + threadIdx.x;
    if (i >= N_NODES) return;
    int cv = cnt[i];
    int ex = incl[i] + bbase[i >> 8] - cv;
    off[i] = ex;
    cursor[i] = ex;
    dinv[i] = rsqrtf((float)cv + 1.0f);
}

// bucket-scatter edges: edata[pos] = {src, norm}
__global__ void k_bucket(const int* __restrict__ ei, const float* __restrict__ dinv,
                         int* __restrict__ cursor, int2* __restrict__ edata) {
    int e = blockIdx.x * 256 + threadIdx.x;
    if (e >= N_EDGES) return;
    int r = ei[e];
    int c = ei[N_EDGES + e];
    int pos = atomicAdd(&cursor[c], 1);
    float nrm = dinv[r] * dinv[c];
    edata[pos] = make_int2(r, __float_as_int(nrm));
}

// ---------- compute ----------

// h1 = x @ W1   [N,128]=[N,128]@[128,128] fp32
// 128-row tile/block, 256 threads; thread computes 8 rows x 8 cols.
// Thread rows strided by 16 (rg + 16*i): the 4 distinct row addresses per
// wave per ds_read_b128 differ by 132 floats == 4 mod 32 banks -> 16 distinct
// banks, conflict-free, with 16-lane broadcast.
__global__ __launch_bounds__(256) void k_gemm1(const float* __restrict__ x,
                                               const float* __restrict__ W1,
                                               float* __restrict__ h1) {
    __shared__ float sx[128][132];   // 66 KB -> 2 blocks/CU
    const int tid = threadIdx.x;
    const int rowBase = blockIdx.x * 128;
#pragma unroll
    for (int j = 0; j < 16; j++) {
        int flat = tid + 256 * j;    // float4 index within 128x128 tile
        int lrow = flat >> 5;        // 32 float4 per row
        int f4 = flat & 31;
        int grow = rowBase + lrow;
        if (grow > N_NODES - 1) grow = N_NODES - 1;  // clamp: wasted compute, guarded store
        float4 v = *(const float4*)(x + (size_t)grow * 128 + f4 * 4);
        *(float4*)(&sx[lrow][f4 * 4]) = v;
    }
    __syncthreads();

    const int cg = tid & 15;
    const int rg = tid >> 4;
    const int c0 = cg * 8;
    float acc[8][8];
#pragma unroll
    for (int i = 0; i < 8; i++)
#pragma unroll
        for (int j = 0; j < 8; j++) acc[i][j] = 0.0f;

    for (int k0 = 0; k0 < 128; k0 += 4) {
        float4 xv[8];
#pragma unroll
        for (int i = 0; i < 8; i++) xv[i] = *(const float4*)(&sx[rg + 16 * i][k0]);
#pragma unroll
        for (int kk = 0; kk < 4; kk++) {
            float4 w0 = *(const float4*)(W1 + (k0 + kk) * 128 + c0);
            float4 w1 = *(const float4*)(W1 + (k0 + kk) * 128 + c0 + 4);
#pragma unroll
            for (int i = 0; i < 8; i++) {
                float xs = (kk == 0) ? xv[i].x : (kk == 1) ? xv[i].y : (kk == 2) ? xv[i].z : xv[i].w;
                acc[i][0] = fmaf(xs, w0.x, acc[i][0]);
                acc[i][1] = fmaf(xs, w0.y, acc[i][1]);
                acc[i][2] = fmaf(xs, w0.z, acc[i][2]);
                acc[i][3] = fmaf(xs, w0.w, acc[i][3]);
                acc[i][4] = fmaf(xs, w1.x, acc[i][4]);
                acc[i][5] = fmaf(xs, w1.y, acc[i][5]);
                acc[i][6] = fmaf(xs, w1.z, acc[i][6]);
                acc[i][7] = fmaf(xs, w1.w, acc[i][7]);
            }
        }
    }

#pragma unroll
    for (int i = 0; i < 8; i++) {
        int grow = rowBase + rg + 16 * i;
        if (grow < N_NODES) {
            float4* o = (float4*)(h1 + (size_t)grow * 128 + c0);
            o[0] = make_float4(acc[i][0], acc[i][1], acc[i][2], acc[i][3]);
            o[1] = make_float4(acc[i][4], acc[i][5], acc[i][6], acc[i][7]);
        }
    }
}

// Layer-1 aggregation (gather over CSR) fused with bias1+ReLU+GEMM2 epilogue.
// One wave per node; lane l owns cols 2l, 2l+1. Writes only h2[N,2].
__global__ __launch_bounds__(256) void k_agg1(const float* __restrict__ h1,
                                              const int2* __restrict__ edata,
                                              const int* __restrict__ off,
                                              const int* __restrict__ cnt,
                                              const float* __restrict__ dinv,
                                              const float* __restrict__ b1,
                                              const float* __restrict__ W2,
                                              float* __restrict__ h2) {
    int g = blockIdx.x * 256 + threadIdx.x;
    int node = g >> 6;   // exact grid: 25000 blocks * 4 waves = 100000 nodes
    int lane = g & 63;
    float d = dinv[node];
    float d2 = d * d;
    float2 a = *(const float2*)(h1 + (size_t)node * 128 + lane * 2);
    a.x *= d2; a.y *= d2;
    int o = off[node];
    int c = cnt[node];   // wave-uniform loop count: no divergence
    for (int i = 0; i < c; i++) {
        int2 sn = edata[o + i];
        float nrm = __int_as_float(sn.y);
        float2 v = *(const float2*)(h1 + (size_t)sn.x * 128 + lane * 2);
        a.x = fmaf(v.x, nrm, a.x);
        a.y = fmaf(v.y, nrm, a.y);
    }
    // epilogue: bias + ReLU + [1x128]@[128x2] via butterfly reduce
    float2 bb = *(const float2*)(b1 + lane * 2);
    float v0 = fmaxf(a.x + bb.x, 0.0f);
    float v1 = fmaxf(a.y + bb.y, 0.0f);
    float4 w = *(const float4*)(W2 + lane * 4);  // W2 rows 2l, 2l+1
    float p0 = v0 * w.x + v1 * w.z;
    float p1 = v0 * w.y + v1 * w.w;
    for (int offl = 32; offl; offl >>= 1) {
        p0 += __shfl_xor(p0, offl);
        p1 += __shfl_xor(p1, offl);
    }
    if (lane == 0) *(float2*)(h2 + (size_t)node * 2) = make_float2(p0, p1);
}

// Layer-2 aggregation: thread per node over same CSR; h2 is L2-resident (800 KB).
__global__ void k_agg2(const float* __restrict__ h2, const int2* __restrict__ edata,
                       const int* __restrict__ off, const int* __restrict__ cnt,
                       const float* __restrict__ dinv, const float* __restrict__ b2,
                       float* __restrict__ out) {
    int n = blockIdx.x * 256 + threadIdx.x;
    if (n >= N_NODES) return;
    float d = dinv[n];
    float d2 = d * d;
    float2 h = *(const float2*)(h2 + (size_t)n * 2);
    float o0 = h.x * d2, o1 = h.y * d2;
    int o = off[n], c = cnt[n];
    for (int i = 0; i < c; i++) {
        int2 sn = edata[o + i];
        float nrm = __int_as_float(sn.y);
        float2 v = *(const float2*)(h2 + (size_t)sn.x * 2);
        o0 = fmaf(v.x, nrm, o0);
        o1 = fmaf(v.y, nrm, o1);
    }
    *(float2*)(out + (size_t)n * 2) = make_float2(o0 + b2[0], o1 + b2[1]);
}

extern "C" void kernel_launch(void* const* d_in, const int* in_sizes, int n_in,
                              void* d_out, int out_size, void* d_ws, size_t ws_size,
                              hipStream_t stream) {
    const float* x  = (const float*)d_in[0];   // [N,128]
    const int* ei   = (const int*)d_in[1];     // [2,E] int32
    const float* W1 = (const float*)d_in[2];   // [128,128]
    const float* b1 = (const float*)d_in[3];   // [128]
    const float* W2 = (const float*)d_in[4];   // [128,2]
    const float* b2 = (const float*)d_in[5];   // [2]
    float* out = (float*)d_out;                // [N,2]

    char* w = (char*)d_ws;
    int*   cnt    = (int*)w;                      w += 100096 * 4;
    int*   incl   = (int*)w;                      w += 100096 * 4;
    int*   bsum   = (int*)w;                      w += 512 * 4;
    int*   bbase  = (int*)w;                      w += 512 * 4;
    int*   off    = (int*)w;                      w += 100096 * 4;
    int*   cursor = (int*)w;                      w += 100096 * 4;
    float* dinv   = (float*)w;                    w += 100096 * 4;
    int2*  edata  = (int2*)w;                     w += (size_t)N_EDGES * 8;
    float* h1     = (float*)w;                    w += (size_t)N_NODES * 128 * 4;
    float* h2     = (float*)w;                    // N*2 floats

    k_zero  <<<391, 256, 0, stream>>>(cnt);
    k_count <<<2344, 256, 0, stream>>>(ei, cnt);
    k_scanA <<<391, 256, 0, stream>>>(cnt, incl, bsum);
    k_scanB <<<1, 512, 0, stream>>>(bsum, bbase);
    k_scanC <<<391, 256, 0, stream>>>(cnt, incl, bbase, off, cursor, dinv);
    k_bucket<<<2344, 256, 0, stream>>>(ei, dinv, cursor, edata);
    k_gemm1 <<<782, 256, 0, stream>>>(x, W1, h1);
    k_agg1  <<<25000, 256, 0, stream>>>(h1, edata, off, cnt, dinv, b1, W2, h2);
    k_agg2  <<<391, 256, 0, stream>>>(h2, edata, off, cnt, dinv, b2, out);
}

// Round 5
// 253.276 us; speedup vs baseline: 5.6024x; 1.1578x over previous
//
#include <hip/hip_runtime.h>
#include <stdint.h>

#define N_NODES 100000
#define N_EDGES 600000
// D_IN = D_H = 128, D_OUT = 2. All float tensors fp32; edge_index int32.
// h1 is stored bf16 (packed ushort) to halve gather traffic in k_agg1.

__device__ __forceinline__ float bflo(unsigned int u) { return __uint_as_float(u << 16); }
__device__ __forceinline__ float bfhi(unsigned int u) { return __uint_as_float(u & 0xffff0000u); }
__device__ __forceinline__ unsigned int f2bf(float f) {  // RNE, returns low 16
    unsigned int u = __float_as_uint(f);
    return (u + 0x7fffu + ((u >> 16) & 1u)) >> 16;
}

// ---------- CSR build ----------

__global__ void k_zero(int* __restrict__ cnt) {
    int i = blockIdx.x * 256 + threadIdx.x;
    if (i < N_NODES) cnt[i] = 0;
}

__global__ void k_count(const int* __restrict__ ei, int* __restrict__ cnt) {
    int e = blockIdx.x * 256 + threadIdx.x;
    if (e < N_EDGES) atomicAdd(&cnt[ei[N_EDGES + e]], 1);
}

// block-level inclusive scan (Hillis-Steele in LDS) + per-block sums
__global__ __launch_bounds__(256) void k_scanA(const int* __restrict__ cnt,
                                               int* __restrict__ incl,
                                               int* __restrict__ bsum) {
    __shared__ int s[256];
    int i = blockIdx.x * 256 + threadIdx.x;
    int v = (i < N_NODES) ? cnt[i] : 0;
    s[threadIdx.x] = v;
    __syncthreads();
    for (int d = 1; d < 256; d <<= 1) {
        int t = (threadIdx.x >= d) ? s[threadIdx.x - d] : 0;
        __syncthreads();
        s[threadIdx.x] += t;
        __syncthreads();
    }
    if (i < N_NODES) incl[i] = s[threadIdx.x];
    if (threadIdx.x == 255) bsum[blockIdx.x] = s[255];
}

__global__ __launch_bounds__(512) void k_scanB(const int* __restrict__ bsum,
                                               int* __restrict__ bbase) {
    __shared__ int s[512];
    int v = (threadIdx.x < 391) ? bsum[threadIdx.x] : 0;
    s[threadIdx.x] = v;
    __syncthreads();
    for (int d = 1; d < 512; d <<= 1) {
        int t = (threadIdx.x >= d) ? s[threadIdx.x - d] : 0;
        __syncthreads();
        s[threadIdx.x] += t;
        __syncthreads();
    }
    if (threadIdx.x < 391) bbase[threadIdx.x] = s[threadIdx.x] - v;  // exclusive
}

__global__ void k_scanC(const int* __restrict__ cnt, const int* __restrict__ incl,
                        const int* __restrict__ bbase, int* __restrict__ off,
                        int* __restrict__ cursor, float* __restrict__ dinv) {
    int i = blockIdx.x * 256 + threadIdx.x;
    if (i >= N_NODES) return;
    int cv = cnt[i];
    int ex = incl[i] + bbase[i >> 8] - cv;
    off[i] = ex;
    cursor[i] = ex;
    dinv[i] = rsqrtf((float)cv + 1.0f);
}

__global__ void k_bucket(const int* __restrict__ ei, const float* __restrict__ dinv,
                         int* __restrict__ cursor, int2* __restrict__ edata) {
    int e = blockIdx.x * 256 + threadIdx.x;
    if (e >= N_EDGES) return;
    int r = ei[e];
    int c = ei[N_EDGES + e];
    int pos = atomicAdd(&cursor[c], 1);
    float nrm = dinv[r] * dinv[c];
    edata[pos] = make_int2(r, __float_as_int(nrm));
}

// ---------- compute ----------

// h1 = bf16(x @ W1)  [N,128]=[N,128]@[128,128] fp32 acc, bf16 store
// 128-row tile/block, 256 threads; thread computes 8 rows x 8 cols.
__global__ __launch_bounds__(256) void k_gemm1(const float* __restrict__ x,
                                               const float* __restrict__ W1,
                                               unsigned short* __restrict__ h1b) {
    __shared__ float sx[128][132];   // row stride 132 == 4 mod 32 banks -> conflict-free
    const int tid = threadIdx.x;
    const int rowBase = blockIdx.x * 128;
#pragma unroll
    for (int j = 0; j < 16; j++) {
        int flat = tid + 256 * j;
        int lrow = flat >> 5;
        int f4 = flat & 31;
        int grow = rowBase + lrow;
        if (grow > N_NODES - 1) grow = N_NODES - 1;
        float4 v = *(const float4*)(x + (size_t)grow * 128 + f4 * 4);
        *(float4*)(&sx[lrow][f4 * 4]) = v;
    }
    __syncthreads();

    const int cg = tid & 15;
    const int rg = tid >> 4;
    const int c0 = cg * 8;
    float acc[8][8];
#pragma unroll
    for (int i = 0; i < 8; i++)
#pragma unroll
        for (int j = 0; j < 8; j++) acc[i][j] = 0.0f;

    for (int k0 = 0; k0 < 128; k0 += 4) {
        float4 xv[8];
#pragma unroll
        for (int i = 0; i < 8; i++) xv[i] = *(const float4*)(&sx[rg + 16 * i][k0]);
#pragma unroll
        for (int kk = 0; kk < 4; kk++) {
            float4 w0 = *(const float4*)(W1 + (k0 + kk) * 128 + c0);
            float4 w1 = *(const float4*)(W1 + (k0 + kk) * 128 + c0 + 4);
#pragma unroll
            for (int i = 0; i < 8; i++) {
                float xs = (kk == 0) ? xv[i].x : (kk == 1) ? xv[i].y : (kk == 2) ? xv[i].z : xv[i].w;
                acc[i][0] = fmaf(xs, w0.x, acc[i][0]);
                acc[i][1] = fmaf(xs, w0.y, acc[i][1]);
                acc[i][2] = fmaf(xs, w0.z, acc[i][2]);
                acc[i][3] = fmaf(xs, w0.w, acc[i][3]);
                acc[i][4] = fmaf(xs, w1.x, acc[i][4]);
                acc[i][5] = fmaf(xs, w1.y, acc[i][5]);
                acc[i][6] = fmaf(xs, w1.z, acc[i][6]);
                acc[i][7] = fmaf(xs, w1.w, acc[i][7]);
            }
        }
    }

#pragma unroll
    for (int i = 0; i < 8; i++) {
        int grow = rowBase + rg + 16 * i;
        if (grow < N_NODES) {
            uint4 p;
            p.x = f2bf(acc[i][0]) | (f2bf(acc[i][1]) << 16);
            p.y = f2bf(acc[i][2]) | (f2bf(acc[i][3]) << 16);
            p.z = f2bf(acc[i][4]) | (f2bf(acc[i][5]) << 16);
            p.w = f2bf(acc[i][6]) | (f2bf(acc[i][7]) << 16);
            *(uint4*)(h1b + (size_t)grow * 128 + c0) = p;
        }
    }
}

// Layer-1 aggregation (bf16 gather over CSR) fused with bias1+ReLU+GEMM2 epilogue.
// One wave per node; lane l owns cols 2l, 2l+1 (one packed uint per row read).
// Edge records preloaded into registers (one per lane), broadcast via __shfl;
// main loop unrolled x4 -> 4 independent row loads in flight.
__global__ __launch_bounds__(256) void k_agg1(const unsigned short* __restrict__ h1b,
                                              const int2* __restrict__ edata,
                                              const int* __restrict__ off,
                                              const int* __restrict__ cnt,
                                              const float* __restrict__ dinv,
                                              const float* __restrict__ b1,
                                              const float* __restrict__ W2,
                                              float* __restrict__ h2) {
    int g = blockIdx.x * 256 + threadIdx.x;
    int node = g >> 6;   // exact grid: 25000 blocks * 4 waves
    int lane = g & 63;
    float d = dinv[node];
    float d2 = d * d;
    unsigned int us = *(const unsigned int*)(h1b + (size_t)node * 128 + lane * 2);
    float ax = bflo(us) * d2, ay = bfhi(us) * d2;

    int o = off[node];
    int c = cnt[node];   // wave-uniform
    int src_l = 0; float nrm_l = 0.0f;
    if (c > 0) {         // uniform branch
        int2 er = edata[o + (lane < c ? lane : c - 1)];
        src_l = er.x; nrm_l = __int_as_float(er.y);
    }
    int cmain = (c < 64) ? c : 64;
    int i = 0;
    for (; i + 4 <= cmain; i += 4) {
        int s0 = __shfl(src_l, i), s1 = __shfl(src_l, i + 1);
        int s2 = __shfl(src_l, i + 2), s3 = __shfl(src_l, i + 3);
        float n0 = __shfl(nrm_l, i), n1 = __shfl(nrm_l, i + 1);
        float n2 = __shfl(nrm_l, i + 2), n3 = __shfl(nrm_l, i + 3);
        unsigned int u0 = *(const unsigned int*)(h1b + (size_t)s0 * 128 + lane * 2);
        unsigned int u1 = *(const unsigned int*)(h1b + (size_t)s1 * 128 + lane * 2);
        unsigned int u2 = *(const unsigned int*)(h1b + (size_t)s2 * 128 + lane * 2);
        unsigned int u3 = *(const unsigned int*)(h1b + (size_t)s3 * 128 + lane * 2);
        ax = fmaf(bflo(u0), n0, ax); ay = fmaf(bfhi(u0), n0, ay);
        ax = fmaf(bflo(u1), n1, ax); ay = fmaf(bfhi(u1), n1, ay);
        ax = fmaf(bflo(u2), n2, ax); ay = fmaf(bfhi(u2), n2, ay);
        ax = fmaf(bflo(u3), n3, ax); ay = fmaf(bfhi(u3), n3, ay);
    }
    for (; i < cmain; i++) {
        int s = __shfl(src_l, i);
        float n = __shfl(nrm_l, i);
        unsigned int u = *(const unsigned int*)(h1b + (size_t)s * 128 + lane * 2);
        ax = fmaf(bflo(u), n, ax); ay = fmaf(bfhi(u), n, ay);
    }
    for (; i < c; i++) {  // deg > 64 tail (essentially never for Poisson(6))
        int2 sn = edata[o + i];
        float n = __int_as_float(sn.y);
        unsigned int u = *(const unsigned int*)(h1b + (size_t)sn.x * 128 + lane * 2);
        ax = fmaf(bflo(u), n, ax); ay = fmaf(bfhi(u), n, ay);
    }

    // epilogue: bias + ReLU + [1x128]@[128x2] via butterfly reduce
    float2 bb = *(const float2*)(b1 + lane * 2);
    float v0 = fmaxf(ax + bb.x, 0.0f);
    float v1 = fmaxf(ay + bb.y, 0.0f);
    float4 w = *(const float4*)(W2 + lane * 4);
    float p0 = v0 * w.x + v1 * w.z;
    float p1 = v0 * w.y + v1 * w.w;
    for (int offl = 32; offl; offl >>= 1) {
        p0 += __shfl_xor(p0, offl);
        p1 += __shfl_xor(p1, offl);
    }
    if (lane == 0) *(float2*)(h2 + (size_t)node * 2) = make_float2(p0, p1);
}

// Layer-2 aggregation: thread per node over same CSR; h2 L2-resident (800 KB).
__global__ void k_agg2(const float* __restrict__ h2, const int2* __restrict__ edata,
                       const int* __restrict__ off, const int* __restrict__ cnt,
                       const float* __restrict__ dinv, const float* __restrict__ b2,
                       float* __restrict__ out) {
    int n = blockIdx.x * 256 + threadIdx.x;
    if (n >= N_NODES) return;
    float d = dinv[n];
    float d2 = d * d;
    float2 h = *(const float2*)(h2 + (size_t)n * 2);
    float o0 = h.x * d2, o1 = h.y * d2;
    int o = off[n], c = cnt[n];
    for (int i = 0; i < c; i++) {
        int2 sn = edata[o + i];
        float nrm = __int_as_float(sn.y);
        float2 v = *(const float2*)(h2 + (size_t)sn.x * 2);
        o0 = fmaf(v.x, nrm, o0);
        o1 = fmaf(v.y, nrm, o1);
    }
    *(float2*)(out + (size_t)n * 2) = make_float2(o0 + b2[0], o1 + b2[1]);
}

extern "C" void kernel_launch(void* const* d_in, const int* in_sizes, int n_in,
                              void* d_out, int out_size, void* d_ws, size_t ws_size,
                              hipStream_t stream) {
    const float* x  = (const float*)d_in[0];   // [N,128]
    const int* ei   = (const int*)d_in[1];     // [2,E] int32
    const float* W1 = (const float*)d_in[2];   // [128,128]
    const float* b1 = (const float*)d_in[3];   // [128]
    const float* W2 = (const float*)d_in[4];   // [128,2]
    const float* b2 = (const float*)d_in[5];   // [2]
    float* out = (float*)d_out;                // [N,2]

    char* w = (char*)d_ws;
    int*   cnt    = (int*)w;                      w += 100096 * 4;
    int*   incl   = (int*)w;                      w += 100096 * 4;
    int*   bsum   = (int*)w;                      w += 512 * 4;
    int*   bbase  = (int*)w;                      w += 512 * 4;
    int*   off    = (int*)w;                      w += 100096 * 4;
    int*   cursor = (int*)w;                      w += 100096 * 4;
    float* dinv   = (float*)w;                    w += 100096 * 4;
    int2*  edata  = (int2*)w;                     w += (size_t)N_EDGES * 8;
    unsigned short* h1b = (unsigned short*)w;     w += (size_t)N_NODES * 128 * 2;
    float* h2     = (float*)w;                    // N*2 floats

    k_zero  <<<391, 256, 0, stream>>>(cnt);
    k_count <<<2344, 256, 0, stream>>>(ei, cnt);
    k_scanA <<<391, 256, 0, stream>>>(cnt, incl, bsum);
    k_scanB <<<1, 512, 0, stream>>>(bsum, bbase);
    k_scanC <<<391, 256, 0, stream>>>(cnt, incl, bbase, off, cursor, dinv);
    k_bucket<<<2344, 256, 0, stream>>>(ei, dinv, cursor, edata);
    k_gemm1 <<<782, 256, 0, stream>>>(x, W1, h1b);
    k_agg1  <<<25000, 256, 0, stream>>>(h1b, edata, off, cnt, dinv, b1, W2, h2);
    k_agg2  <<<391, 256, 0, stream>>>(h2, edata, off, cnt, dinv, b2, out);
}

// Round 6
// 218.635 us; speedup vs baseline: 6.4901x; 1.1584x over previous
//
#include <hip/hip_runtime.h>
#include <stdint.h>

#define N_NODES 100000
#define N_EDGES 600000
// D_IN = D_H = 128, D_OUT = 2. All float tensors fp32; edge_index int32.
// h1 stored bf16; GEMM1 runs on MFMA bf16 (x, W1 cast to bf16; f32 accumulate).

typedef __attribute__((ext_vector_type(8))) short bf16x8;
typedef __attribute__((ext_vector_type(4))) float f32x4;

__device__ __forceinline__ float bflo(unsigned int u) { return __uint_as_float(u << 16); }
__device__ __forceinline__ float bfhi(unsigned int u) { return __uint_as_float(u & 0xffff0000u); }
__device__ __forceinline__ unsigned int f2bf(float f) {  // RNE, returns low 16
    unsigned int u = __float_as_uint(f);
    return (u + 0x7fffu + ((u >> 16) & 1u)) >> 16;
}

// ---------- CSR build ----------

__global__ void k_zero(int* __restrict__ cnt) {
    int i = blockIdx.x * 256 + threadIdx.x;
    if (i < N_NODES) cnt[i] = 0;
}

__global__ void k_count(const int* __restrict__ ei, int* __restrict__ cnt) {
    int e = blockIdx.x * 256 + threadIdx.x;
    if (e < N_EDGES) atomicAdd(&cnt[ei[N_EDGES + e]], 1);
}

__global__ __launch_bounds__(256) void k_scanA(const int* __restrict__ cnt,
                                               int* __restrict__ incl,
                                               int* __restrict__ bsum) {
    __shared__ int s[256];
    int i = blockIdx.x * 256 + threadIdx.x;
    int v = (i < N_NODES) ? cnt[i] : 0;
    s[threadIdx.x] = v;
    __syncthreads();
    for (int d = 1; d < 256; d <<= 1) {
        int t = (threadIdx.x >= d) ? s[threadIdx.x - d] : 0;
        __syncthreads();
        s[threadIdx.x] += t;
        __syncthreads();
    }
    if (i < N_NODES) incl[i] = s[threadIdx.x];
    if (threadIdx.x == 255) bsum[blockIdx.x] = s[255];
}

__global__ __launch_bounds__(512) void k_scanB(const int* __restrict__ bsum,
                                               int* __restrict__ bbase) {
    __shared__ int s[512];
    int v = (threadIdx.x < 391) ? bsum[threadIdx.x] : 0;
    s[threadIdx.x] = v;
    __syncthreads();
    for (int d = 1; d < 512; d <<= 1) {
        int t = (threadIdx.x >= d) ? s[threadIdx.x - d] : 0;
        __syncthreads();
        s[threadIdx.x] += t;
        __syncthreads();
    }
    if (threadIdx.x < 391) bbase[threadIdx.x] = s[threadIdx.x] - v;  // exclusive
}

__global__ void k_scanC(const int* __restrict__ cnt, const int* __restrict__ incl,
                        const int* __restrict__ bbase, int* __restrict__ off,
                        int* __restrict__ cursor, float* __restrict__ dinv) {
    int i = blockIdx.x * 256 + threadIdx.x;
    if (i >= N_NODES) return;
    int cv = cnt[i];
    int ex = incl[i] + bbase[i >> 8] - cv;
    off[i] = ex;
    cursor[i] = ex;
    dinv[i] = rsqrtf((float)cv + 1.0f);
}

__global__ void k_bucket(const int* __restrict__ ei, const float* __restrict__ dinv,
                         int* __restrict__ cursor, int2* __restrict__ edata) {
    int e = blockIdx.x * 256 + threadIdx.x;
    if (e >= N_EDGES) return;
    int r = ei[e];
    int c = ei[N_EDGES + e];
    int pos = atomicAdd(&cursor[c], 1);
    float nrm = dinv[r] * dinv[c];
    edata[pos] = make_int2(r, __float_as_int(nrm));
}

// ---------- compute ----------

// W1T[n][k] = bf16(W1[k][n])  (tiny one-off transpose+cast, L2-resident)
__global__ void k_w1t(const float* __restrict__ W1, unsigned short* __restrict__ W1Tb) {
    int idx = blockIdx.x * 256 + threadIdx.x;  // 16384
    int n = idx >> 7, k = idx & 127;
    W1Tb[n * 128 + k] = (unsigned short)f2bf(W1[k * 128 + n]);
}

// h1b = bf16(x @ W1) via MFMA bf16. 64 rows/block, 4 waves; wave w owns rows
// [16w,16w+16) x all 128 cols = 8 col-tiles. LDS stride 136 ushort: row*68
// words == row*4 mod 32 banks -> quad-row frag reads alias <=2-way (free).
__global__ __launch_bounds__(256) void k_gemm1(const float* __restrict__ x,
                                               const unsigned short* __restrict__ W1Tb,
                                               unsigned short* __restrict__ h1b) {
    __shared__ unsigned short sxb[64][136];   // x tile, bf16; reused for D staging
    __shared__ unsigned short sw[128][136];   // W1T, bf16
    const int tid = threadIdx.x;
    const int rowBase = blockIdx.x * 64;
#pragma unroll
    for (int i = 0; i < 8; i++) {            // stage x: 2048 float4 -> bf16
        int flat = tid + 256 * i;
        int row = flat >> 5;
        int f4 = flat & 31;
        int grow = rowBase + row;
        if (grow > N_NODES - 1) grow = N_NODES - 1;
        float4 v = *(const float4*)(x + (size_t)grow * 128 + f4 * 4);
        ushort4 p;
        p.x = (unsigned short)f2bf(v.x);
        p.y = (unsigned short)f2bf(v.y);
        p.z = (unsigned short)f2bf(v.z);
        p.w = (unsigned short)f2bf(v.w);
        *(ushort4*)(&sxb[row][f4 * 4]) = p;
    }
#pragma unroll
    for (int i = 0; i < 8; i++) {            // stage W1T: 2048 uint4
        int flat = tid + 256 * i;
        int row = flat >> 4;
        int c8 = flat & 15;
        uint4 v = *(const uint4*)(W1Tb + row * 128 + c8 * 8);
        *(uint4*)(&sw[row][c8 * 8]) = v;
    }
    __syncthreads();

    const int wv = tid >> 6;
    const int lane = tid & 63;
    const int l16 = lane & 15;
    const int quad = lane >> 4;
    f32x4 acc[8];
#pragma unroll
    for (int t = 0; t < 8; t++) acc[t] = (f32x4){0.f, 0.f, 0.f, 0.f};

#pragma unroll
    for (int k0 = 0; k0 < 128; k0 += 32) {
        bf16x8 a = *(const bf16x8*)(&sxb[wv * 16 + l16][k0 + quad * 8]);
#pragma unroll
        for (int t = 0; t < 8; t++) {
            bf16x8 b = *(const bf16x8*)(&sw[t * 16 + l16][k0 + quad * 8]);
            acc[t] = __builtin_amdgcn_mfma_f32_16x16x32_bf16(a, b, acc[t], 0, 0, 0);
        }
    }
    __syncthreads();                          // LDS reads done; reuse sxb for D
#pragma unroll
    for (int t = 0; t < 8; t++)
#pragma unroll
        for (int r = 0; r < 4; r++)
            sxb[wv * 16 + quad * 4 + r][t * 16 + l16] = (unsigned short)f2bf(acc[t][r]);
    __syncthreads();
#pragma unroll
    for (int i = 0; i < 4; i++) {             // coalesced store: 1024 uint4
        int flat = tid + 256 * i;
        int row = flat >> 4;
        int c8 = flat & 15;
        int grow = rowBase + row;
        if (grow < N_NODES)
            *(uint4*)(h1b + (size_t)grow * 128 + c8 * 8) = *(const uint4*)(&sxb[row][c8 * 8]);
    }
}

// Layer-1 aggregation (bf16 gather over CSR) fused with bias1+ReLU+GEMM2 epilogue.
__global__ __launch_bounds__(256) void k_agg1(const unsigned short* __restrict__ h1b,
                                              const int2* __restrict__ edata,
                                              const int* __restrict__ off,
                                              const int* __restrict__ cnt,
                                              const float* __restrict__ dinv,
                                              const float* __restrict__ b1,
                                              const float* __restrict__ W2,
                                              float* __restrict__ h2) {
    int g = blockIdx.x * 256 + threadIdx.x;
    int node = g >> 6;   // exact grid: 25000 blocks * 4 waves
    int lane = g & 63;
    float d = dinv[node];
    float d2 = d * d;
    unsigned int us = *(const unsigned int*)(h1b + (size_t)node * 128 + lane * 2);
    float ax = bflo(us) * d2, ay = bfhi(us) * d2;

    int o = off[node];
    int c = cnt[node];   // wave-uniform
    int src_l = 0; float nrm_l = 0.0f;
    if (c > 0) {
        int2 er = edata[o + (lane < c ? lane : c - 1)];
        src_l = er.x; nrm_l = __int_as_float(er.y);
    }
    int cmain = (c < 64) ? c : 64;
    int i = 0;
    for (; i + 4 <= cmain; i += 4) {
        int s0 = __shfl(src_l, i), s1 = __shfl(src_l, i + 1);
        int s2 = __shfl(src_l, i + 2), s3 = __shfl(src_l, i + 3);
        float n0 = __shfl(nrm_l, i), n1 = __shfl(nrm_l, i + 1);
        float n2 = __shfl(nrm_l, i + 2), n3 = __shfl(nrm_l, i + 3);
        unsigned int u0 = *(const unsigned int*)(h1b + (size_t)s0 * 128 + lane * 2);
        unsigned int u1 = *(const unsigned int*)(h1b + (size_t)s1 * 128 + lane * 2);
        unsigned int u2 = *(const unsigned int*)(h1b + (size_t)s2 * 128 + lane * 2);
        unsigned int u3 = *(const unsigned int*)(h1b + (size_t)s3 * 128 + lane * 2);
        ax = fmaf(bflo(u0), n0, ax); ay = fmaf(bfhi(u0), n0, ay);
        ax = fmaf(bflo(u1), n1, ax); ay = fmaf(bfhi(u1), n1, ay);
        ax = fmaf(bflo(u2), n2, ax); ay = fmaf(bfhi(u2), n2, ay);
        ax = fmaf(bflo(u3), n3, ax); ay = fmaf(bfhi(u3), n3, ay);
    }
    for (; i < cmain; i++) {
        int s = __shfl(src_l, i);
        float n = __shfl(nrm_l, i);
        unsigned int u = *(const unsigned int*)(h1b + (size_t)s * 128 + lane * 2);
        ax = fmaf(bflo(u), n, ax); ay = fmaf(bfhi(u), n, ay);
    }
    for (; i < c; i++) {  // deg > 64 tail (essentially never for Poisson(6))
        int2 sn = edata[o + i];
        float n = __int_as_float(sn.y);
        unsigned int u = *(const unsigned int*)(h1b + (size_t)sn.x * 128 + lane * 2);
        ax = fmaf(bflo(u), n, ax); ay = fmaf(bfhi(u), n, ay);
    }

    float2 bb = *(const float2*)(b1 + lane * 2);
    float v0 = fmaxf(ax + bb.x, 0.0f);
    float v1 = fmaxf(ay + bb.y, 0.0f);
    float4 w = *(const float4*)(W2 + lane * 4);
    float p0 = v0 * w.x + v1 * w.z;
    float p1 = v0 * w.y + v1 * w.w;
    for (int offl = 32; offl; offl >>= 1) {
        p0 += __shfl_xor(p0, offl);
        p1 += __shfl_xor(p1, offl);
    }
    if (lane == 0) *(float2*)(h2 + (size_t)node * 2) = make_float2(p0, p1);
}

// Layer-2 aggregation: thread per node over same CSR; h2 L2-resident (800 KB).
__global__ void k_agg2(const float* __restrict__ h2, const int2* __restrict__ edata,
                       const int* __restrict__ off, const int* __restrict__ cnt,
                       const float* __restrict__ dinv, const float* __restrict__ b2,
                       float* __restrict__ out) {
    int n = blockIdx.x * 256 + threadIdx.x;
    if (n >= N_NODES) return;
    float d = dinv[n];
    float d2 = d * d;
    float2 h = *(const float2*)(h2 + (size_t)n * 2);
    float o0 = h.x * d2, o1 = h.y * d2;
    int o = off[n], c = cnt[n];
    for (int i = 0; i < c; i++) {
        int2 sn = edata[o + i];
        float nrm = __int_as_float(sn.y);
        float2 v = *(const float2*)(h2 + (size_t)sn.x * 2);
        o0 = fmaf(v.x, nrm, o0);
        o1 = fmaf(v.y, nrm, o1);
    }
    *(float2*)(out + (size_t)n * 2) = make_float2(o0 + b2[0], o1 + b2[1]);
}

extern "C" void kernel_launch(void* const* d_in, const int* in_sizes, int n_in,
                              void* d_out, int out_size, void* d_ws, size_t ws_size,
                              hipStream_t stream) {
    const float* x  = (const float*)d_in[0];   // [N,128]
    const int* ei   = (const int*)d_in[1];     // [2,E] int32
    const float* W1 = (const float*)d_in[2];   // [128,128]
    const float* b1 = (const float*)d_in[3];   // [128]
    const float* W2 = (const float*)d_in[4];   // [128,2]
    const float* b2 = (const float*)d_in[5];   // [2]
    float* out = (float*)d_out;                // [N,2]

    char* w = (char*)d_ws;
    int*   cnt    = (int*)w;                      w += 100096 * 4;
    int*   incl   = (int*)w;                      w += 100096 * 4;
    int*   bsum   = (int*)w;                      w += 512 * 4;
    int*   bbase  = (int*)w;                      w += 512 * 4;
    int*   off    = (int*)w;                      w += 100096 * 4;
    int*   cursor = (int*)w;                      w += 100096 * 4;
    float* dinv   = (float*)w;                    w += 100096 * 4;
    int2*  edata  = (int2*)w;                     w += (size_t)N_EDGES * 8;
    unsigned short* h1b = (unsigned short*)w;     w += (size_t)N_NODES * 128 * 2;
    float* h2     = (float*)w;                    w += (size_t)N_NODES * 2 * 4;
    unsigned short* W1Tb = (unsigned short*)w;    // 128*128 ushort

    k_zero  <<<391, 256, 0, stream>>>(cnt);
    k_count <<<2344, 256, 0, stream>>>(ei, cnt);
    k_scanA <<<391, 256, 0, stream>>>(cnt, incl, bsum);
    k_scanB <<<1, 512, 0, stream>>>(bsum, bbase);
    k_scanC <<<391, 256, 0, stream>>>(cnt, incl, bbase, off, cursor, dinv);
    k_bucket<<<2344, 256, 0, stream>>>(ei, dinv, cursor, edata);
    k_w1t   <<<64, 256, 0, stream>>>(W1, W1Tb);
    k_gemm1 <<<1563, 256, 0, stream>>>(x, W1Tb, h1b);
    k_agg1  <<<25000, 256, 0, stream>>>(h1b, edata, off, cnt, dinv, b1, W2, h2);
    k_agg2  <<<391, 256, 0, stream>>>(h2, edata, off, cnt, dinv, b2, out);
}